// Round 1
// 310.736 us; speedup vs baseline: 1.0298x; 1.0298x over previous
//
#include <hip/hip_runtime.h>
#include <hip/hip_bf16.h>

#define B_    16
#define CIN   64
#define Hn    64
#define Wn    64
#define HID   128
#define SXS2  72    // sX2 row stride in shorts (144B, 16B-aligned)
#define SHS   136   // sH  row stride in shorts (272B, 16B-aligned)
#define NJC   8     // j-chunks per batch (16 channels each)
#define NBLK  (B_ * NJC)

typedef __attribute__((ext_vector_type(8))) short bfrag_t;   // 8 bf16 (4 VGPRs)
typedef __attribute__((ext_vector_type(4))) float f4_t;

// d_ws layout:
//   [0, 256KB)        : h_buf[0]  bf16 [16][64][128]   (b, w, ci)
//   [256KB, 512KB)    : h_buf[1]  (step h writes buf[h&1], reads buf[h&1^1])
//   [512KB, +4KB)     : per-b barrier counters, one per 256B line
#define HBUF_SHORTS (B_ * Wn * HID)
#define HBUF_BYTES  (HBUF_SHORTS * 2)
#define CNT_STRIDE  256

static __device__ __forceinline__ short f2bf(float f) {
    union { __hip_bfloat16 h; short s; } u;
    u.h = __float2bfloat16(f);
    return u.s;
}
static __device__ __forceinline__ float sigm(float z)  { return 1.f / (1.f + __expf(-z)); }
static __device__ __forceinline__ float tanhf_(float z){ return 2.f / (1.f + __expf(-2.f * z)) - 1.f; }

extern "C" __global__ __launch_bounds__(256, 1)
void rowlstm_kernel(const float* __restrict__ x,
                    const float* __restrict__ w_is,
                    const float* __restrict__ b_is,
                    const float* __restrict__ w_ss,
                    const float* __restrict__ b_ss,
                    float* __restrict__ out,
                    unsigned char* __restrict__ ws)
{
    const int tid  = threadIdx.x;
    const int bid  = blockIdx.x;
    const int b    = bid & 15;        // batch; same-b blocks share bid%8 -> same XCD (perf heuristic only)
    const int jc   = bid >> 4;        // j-chunk: channels [jc*16, jc*16+16)
    const int lane = tid & 63;
    const int wv   = tid >> 6;        // wave id = N-tile (16 w's)
    const int l15  = lane & 15;
    const int quad = lane >> 4;

    short*    hbuf0 = (short*)ws;
    unsigned* cnt   = (unsigned*)(ws + 2 * HBUF_BYTES + b * CNT_STRIDE);

    // LDS ~27 KB. Shifted-read panels: tap t of column w' reads row w'+t.
    __shared__ alignas(16) short sH[66 * SHS];    // h panel, rows 0..65 (0,65 = zero guards)
    __shared__ alignas(16) short sX2[65 * SXS2];  // x panel, rows 0..64 (0 = zero guard)

    // ---- A (weight) fragments, gate-major: M-row = mt*16 + l15 -> gate mt, ch l15.
    // K layout (512): [0,64) x kw0 | [64,128) x kw1 | [128,256) h kw0 | [256,384) h kw1 | [384,512) h kw2
    bfrag_t a_frag[4][16];
    #pragma unroll
    for (int mt = 0; mt < 4; ++mt) {
        const int co = mt * HID + jc * 16 + l15;
        #pragma unroll
        for (int kt = 0; kt < 16; ++kt) {
            const int kk0 = kt * 32 + quad * 8;   // region constant per (kt,quad): boundaries are 32-aligned
            const float* p;
            if      (kt < 2)  p = &w_is[(co * CIN + kk0)         * 3 + 0];
            else if (kt < 4)  p = &w_is[(co * CIN + (kk0 - 64))  * 3 + 1];
            else if (kt < 8)  p = &w_ss[(co * HID + (kk0 - 128)) * 3 + 0];
            else if (kt < 12) p = &w_ss[(co * HID + (kk0 - 256)) * 3 + 1];
            else              p = &w_ss[(co * HID + (kk0 - 384)) * 3 + 2];
            bfrag_t v;
            #pragma unroll
            for (int j = 0; j < 8; ++j) v[j] = f2bf(p[j * 3]);
            a_frag[mt][kt] = v;
        }
    }

    // per-thread biases: 4 gates x 4 channels (this thread's channels = quad*4 + r)
    float bias[4][4];
    #pragma unroll
    for (int g = 0; g < 4; ++g) {
        #pragma unroll
        for (int r = 0; r < 4; ++r) {
            const int co = g * HID + jc * 16 + quad * 4 + r;
            bias[g][r] = b_is[co] + b_ss[co];
        }
    }

    // zero guard rows (never touched again)
    {
        bfrag_t z8 = {0,0,0,0,0,0,0,0};
        if (tid < 8)  *(bfrag_t*)&sX2[tid * 8] = z8;                 // sX2 row 0 (64 ci)
        if (tid < 16) {
            *(bfrag_t*)&sH[tid * 8] = z8;                            // sH row 0
            *(bfrag_t*)&sH[65 * SHS + tid * 8] = z8;                 // sH row 65
        }
    }

    float creg[4] = {0.f, 0.f, 0.f, 0.f};
    const int wp  = wv * 16 + l15;    // this thread's w (GEMM col and phase C)

    // x staging: thread (xw, xc2) holds x[ci = xc2*16 .. +15][xw] for the current row
    const int xw  = tid & 63;
    const int xc2 = tid >> 6;
    float xr[16];
    #pragma unroll
    for (int e = 0; e < 16; ++e)
        xr[e] = x[((b * CIN + xc2 * 16 + e) * Hn + 0) * Wn + xw];

    const int cig = tid & 15;
    const int w0  = tid >> 4;

    for (int h = 0; h < Hn; ++h) {
        const short* rd_hb = hbuf0 + ((h & 1) ^ 1) * HBUF_SHORTS + b * Wn * HID;
        short*       wr_hb = hbuf0 + (h & 1) * HBUF_SHORTS + b * Wn * HID;

        // ---- all-thread spin: wait until all NJC blocks of batch b finished row h-1 ----
        if (h > 0) {
            const unsigned target = (unsigned)(NJC * h);
            while (__hip_atomic_load(cnt, __ATOMIC_RELAXED, __HIP_MEMORY_SCOPE_AGENT) < target)
                __builtin_amdgcn_s_sleep(1);
            asm volatile("" ::: "memory");   // keep the h-data loads below the spin
        }

        // ---- issue h-panel loads (LLC) immediately after release ----
        union { bfrag_t f; unsigned long long q[2]; } hu0, hu1, hu2, hu3;
        if (h > 0) {
            const unsigned long long* s0 = (const unsigned long long*)(rd_hb + (w0 +  0) * HID + cig * 8);
            const unsigned long long* s1 = (const unsigned long long*)(rd_hb + (w0 + 16) * HID + cig * 8);
            const unsigned long long* s2 = (const unsigned long long*)(rd_hb + (w0 + 32) * HID + cig * 8);
            const unsigned long long* s3 = (const unsigned long long*)(rd_hb + (w0 + 48) * HID + cig * 8);
            hu0.q[0] = __hip_atomic_load(s0,     __ATOMIC_RELAXED, __HIP_MEMORY_SCOPE_AGENT);
            hu0.q[1] = __hip_atomic_load(s0 + 1, __ATOMIC_RELAXED, __HIP_MEMORY_SCOPE_AGENT);
            hu1.q[0] = __hip_atomic_load(s1,     __ATOMIC_RELAXED, __HIP_MEMORY_SCOPE_AGENT);
            hu1.q[1] = __hip_atomic_load(s1 + 1, __ATOMIC_RELAXED, __HIP_MEMORY_SCOPE_AGENT);
            hu2.q[0] = __hip_atomic_load(s2,     __ATOMIC_RELAXED, __HIP_MEMORY_SCOPE_AGENT);
            hu2.q[1] = __hip_atomic_load(s2 + 1, __ATOMIC_RELAXED, __HIP_MEMORY_SCOPE_AGENT);
            hu3.q[0] = __hip_atomic_load(s3,     __ATOMIC_RELAXED, __HIP_MEMORY_SCOPE_AGENT);
            hu3.q[1] = __hip_atomic_load(s3 + 1, __ATOMIC_RELAXED, __HIP_MEMORY_SCOPE_AGENT);
        } else {
            hu0.q[0] = hu0.q[1] = 0ull; hu1.q[0] = hu1.q[1] = 0ull;
            hu2.q[0] = hu2.q[1] = 0ull; hu3.q[0] = hu3.q[1] = 0ull;
        }

        // ---- build x panel (row h) from xr loaded last iteration; overlaps h-load latency ----
        {
            bfrag_t v0, v1;
            #pragma unroll
            for (int e = 0; e < 8; ++e) { v0[e] = f2bf(xr[e]); v1[e] = f2bf(xr[e + 8]); }
            *(bfrag_t*)&sX2[(xw + 1) * SXS2 + xc2 * 16]     = v0;
            *(bfrag_t*)&sX2[(xw + 1) * SXS2 + xc2 * 16 + 8] = v1;
        }
        // ---- issue x loads for the NEXT row now; they drain at S2, far off the arrive path ----
        {
            const int hp = (h < Hn - 1) ? h + 1 : h;
            #pragma unroll
            for (int e = 0; e < 16; ++e)
                xr[e] = x[((b * CIN + xc2 * 16 + e) * Hn + hp) * Wn + xw];
        }
        // ---- h panel writes (compiler inserts the precise vmcnt for hu*) ----
        *(bfrag_t*)&sH[(w0 +  1) * SHS + cig * 8] = hu0.f;
        *(bfrag_t*)&sH[(w0 + 17) * SHS + cig * 8] = hu1.f;
        *(bfrag_t*)&sH[(w0 + 33) * SHS + cig * 8] = hu2.f;
        *(bfrag_t*)&sH[(w0 + 49) * SHS + cig * 8] = hu3.f;

        __syncthreads();   // S1: panels ready

        // ---- GEMM, single pass K=512, gate-major M=64 ----
        f4_t acc0 = {0.f,0.f,0.f,0.f}, acc1 = {0.f,0.f,0.f,0.f};
        f4_t acc2 = {0.f,0.f,0.f,0.f}, acc3 = {0.f,0.f,0.f,0.f};
        #pragma unroll
        for (int kt = 0; kt < 16; ++kt) {
            const short* src;
            if (kt < 4) {                         // x taps: t = kt>>1
                src = &sX2[(wp + (kt >> 1)) * SXS2 + (kt & 1) * 32 + quad * 8];
            } else {                              // h taps: t = (kt-4)>>2
                src = &sH[(wp + ((kt - 4) >> 2)) * SHS + ((kt - 4) & 3) * 32 + quad * 8];
            }
            bfrag_t bf = *(const bfrag_t*)src;
            acc0 = __builtin_amdgcn_mfma_f32_16x16x32_bf16(a_frag[0][kt], bf, acc0, 0, 0, 0);
            acc1 = __builtin_amdgcn_mfma_f32_16x16x32_bf16(a_frag[1][kt], bf, acc1, 0, 0, 0);
            acc2 = __builtin_amdgcn_mfma_f32_16x16x32_bf16(a_frag[2][kt], bf, acc2, 0, 0, 0);
            acc3 = __builtin_amdgcn_mfma_f32_16x16x32_bf16(a_frag[3][kt], bf, acc3, 0, 0, 0);
        }

        // ---- phase C: fully lane-local. acc_mt[r] = z[gate mt][ch quad*4+r][w=wp] ----
        float hv[4];
        #pragma unroll
        for (int r = 0; r < 4; ++r) {
            float ig = sigm (acc0[r] + bias[0][r]);
            float fg = sigm (acc1[r] + bias[1][r]);
            float og = sigm (acc2[r] + bias[2][r]);
            float gg = tanhf_(acc3[r] + bias[3][r]);
            float c  = fg * creg[r] + ig * gg;
            creg[r]  = c;
            hv[r]    = og * tanhf_(c);
            out[((b * HID + jc * 16 + quad * 4 + r) * Hn + h) * Wn + wp] = hv[r];
        }
        // packed 4x bf16 (8B) -> LLC write-through (agent-scope relaxed atomic)
        {
            unsigned p0 = (unsigned)(unsigned short)f2bf(hv[0]) |
                          ((unsigned)(unsigned short)f2bf(hv[1]) << 16);
            unsigned p1 = (unsigned)(unsigned short)f2bf(hv[2]) |
                          ((unsigned)(unsigned short)f2bf(hv[3]) << 16);
            unsigned long long pk = (unsigned long long)p0 | ((unsigned long long)p1 << 32);
            unsigned long long* dst = (unsigned long long*)(wr_hb + wp * HID + jc * 16 + quad * 4);
            __hip_atomic_store(dst, pk, __ATOMIC_RELAXED, __HIP_MEMORY_SCOPE_AGENT);
        }

        __syncthreads();   // S2: drains all stores (vmcnt 0) + syncs waves -> safe to arrive

        if (h < Hn - 1 && tid == 0)
            __hip_atomic_fetch_add(cnt, 1u, __ATOMIC_RELAXED, __HIP_MEMORY_SCOPE_AGENT);
    }
}

extern "C" void kernel_launch(void* const* d_in, const int* in_sizes, int n_in,
                              void* d_out, int out_size, void* d_ws, size_t ws_size,
                              hipStream_t stream) {
    const float* x    = (const float*)d_in[0];
    const float* w_is = (const float*)d_in[1];
    const float* b_is = (const float*)d_in[2];
    const float* w_ss = (const float*)d_in[3];
    const float* b_ss = (const float*)d_in[4];
    float* out = (float*)d_out;
    unsigned char* ws = (unsigned char*)d_ws;

    hipMemsetAsync(ws + 2 * HBUF_BYTES, 0, B_ * CNT_STRIDE, stream);

    // 128 blocks (8 j-chunks x 16 batches), 27KB LDS, 1 block/CU -> all co-resident.
    rowlstm_kernel<<<dim3(NBLK), dim3(256), 0, stream>>>(x, w_is, b_is, w_ss, b_ss, out, ws);
}